// Round 18
// baseline (297.930 us; speedup 1.0000x reference)
//
#include <hip/hip_runtime.h>
#include <hip/hip_bf16.h>

typedef short bf16x8 __attribute__((ext_vector_type(8)));
typedef float f32x4 __attribute__((ext_vector_type(4)));

#define LN_EPS 1e-5f
#define SLOPE 0.2f

// Native conversion: compiler fuses adjacent pairs to v_cvt_pk_bf16_f32 (m240).
__device__ __forceinline__ unsigned short f2bf(float f){
  __hip_bfloat16 b = __float2bfloat16(f);
  return *reinterpret_cast<unsigned short*>(&b);
}

// Verified W image (rounds 1..17):
// wbf[((s*4+g)*512 + c)*8 + j] = W[k = s*32+g*8+j][c]   (c<256: W_l, else W_r)
__global__ void wconv_kernel(const float* __restrict__ Wl,
                             const float* __restrict__ Wr,
                             unsigned short* __restrict__ wbf){
  int idx = blockIdx.x * 256 + threadIdx.x;   // 0..16383 : (s,g,c)
  int c = idx & 511;
  int gg = (idx >> 9) & 3;
  int s = idx >> 11;
  int k0 = s * 32 + gg * 8;
  const float* src = (c < 256) ? (Wl + c) : (Wr + (c - 256));
  bf16x8 v;
  #pragma unroll
  for (int j = 0; j < 8; ++j) v[j] = (short)f2bf(src[(k0 + j) * 256]);
  *(bf16x8*)&wbf[(size_t)idx * 8] = v;
}

// R17 verified algebra, PERSISTENT blocks + double-buffered h-tile:
// each block loops over tiles (stride = grid); next tile's h f32 loads are
// issued before/within the attention phase and written to the other LDS half,
// so the next k-loop starts warm (cross-tile pipelining; T14 issue-early /
// write-late at tile granularity). Staging values and attention math verbatim.
// NOTE: minwaves/EU >= 4 in __launch_bounds__ MISCOMPILES (R5->R6 test). Keep 2.
template<bool USE_WS>
__global__ __launch_bounds__(256, 2)
void gat_fused(const float* __restrict__ hin, const float* __restrict__ ebias,
               const float* __restrict__ Wl, const float* __restrict__ Wr,
               const float* __restrict__ avec, const float* __restrict__ gmw,
               const float* __restrict__ btw, const unsigned short* __restrict__ wbf,
               float* __restrict__ out, int ntiles){
  __shared__ __align__(16) unsigned short uni[16384];   // 2 x 16KB h-tile halves
  __shared__ float red1[128], red2[128];
  __shared__ float eb_s[16];

  const int t = threadIdx.x;
  const int lane = t & 63;
  const int w = t >> 6;
  const int g = lane >> 4;
  const int ln = lane & 15;
  const int stride = gridDim.x;

  float av[4];
  #pragma unroll
  for (int c = 0; c < 4; ++c) av[c] = avec[w * 64 + c * 16 + ln];
  if (t < 16) eb_s[t] = ebias[t];

  int tile = blockIdx.x;
  if (tile >= ntiles) return;

  // ---- prologue: stage tile into half 0 (verified R4 pattern)
  {
    const float* hb = hin + (size_t)tile * 8192;
    #pragma unroll
    for (int it = 0; it < 4; ++it){
      int q = it * 256 + t;
      int row = q >> 5;
      int c = q & 31;
      const float* src = hb + row * 256 + c * 8;
      float4 f0 = *(const float4*)src;
      float4 f1 = *(const float4*)(src + 4);
      bf16x8 v;
      v[0]=(short)f2bf(f0.x); v[1]=(short)f2bf(f0.y); v[2]=(short)f2bf(f0.z); v[3]=(short)f2bf(f0.w);
      v[4]=(short)f2bf(f1.x); v[5]=(short)f2bf(f1.y); v[6]=(short)f2bf(f1.z); v[7]=(short)f2bf(f1.w);
      *(bf16x8*)&uni[row * 256 + ((c ^ (row & 7)) << 3)] = v;
    }
  }
  int cur = 0;

  for (;;){
    __syncthreads();                     // uni[cur] fully staged for all waves
    unsigned short* ub = &uni[cur * 8192];

    f32x4 acc[2][8];
    #pragma unroll
    for (int m = 0; m < 2; ++m)
      #pragma unroll
      for (int c = 0; c < 8; ++c)
        acc[m][c] = (f32x4){0.f, 0.f, 0.f, 0.f};

    // ---- pipelined K loop (R17 verbatim, base = ub)
    if constexpr (USE_WS){
      const unsigned short* wbase = wbf + (size_t)g * 4096 + (size_t)(w * 64 + ln) * 8;
      bf16x8 af[2], afn[2], P[4], Q[4];
      #pragma unroll
      for (int m = 0; m < 2; ++m)
        af[m] = *(const bf16x8*)&ub[(m * 16 + ln) * 256 + ((g ^ (ln & 7)) << 3)];
      #pragma unroll
      for (int c = 0; c < 4; ++c)
        P[c] = *(const bf16x8*)(wbase + c * 128);          // gl(0)
      #pragma unroll
      for (int step = 0; step < 8; ++step){
        const unsigned short* wp = wbase + (size_t)step * 16384;
        #pragma unroll
        for (int c = 0; c < 4; ++c)
          Q[c] = *(const bf16x8*)(wp + 2048 + c * 128);    // gr(step)
        if (step < 7){
          #pragma unroll
          for (int m = 0; m < 2; ++m)
            afn[m] = *(const bf16x8*)&ub[(m * 16 + ln) * 256
                       + ((((step + 1) * 4 + g) ^ (ln & 7)) << 3)];
        }
        __builtin_amdgcn_s_setprio(1);
        #pragma unroll
        for (int m = 0; m < 2; ++m)
          #pragma unroll
          for (int c = 0; c < 4; ++c)
            acc[m][c] = __builtin_amdgcn_mfma_f32_16x16x32_bf16(af[m], P[c], acc[m][c], 0, 0, 0);
        __builtin_amdgcn_s_setprio(0);
        if (step < 7){
          const unsigned short* wpn = wp + 16384;
          #pragma unroll
          for (int c = 0; c < 4; ++c)
            P[c] = *(const bf16x8*)(wpn + c * 128);        // gl(step+1)
        }
        __builtin_amdgcn_s_setprio(1);
        #pragma unroll
        for (int m = 0; m < 2; ++m)
          #pragma unroll
          for (int c = 0; c < 4; ++c)
            acc[m][c + 4] = __builtin_amdgcn_mfma_f32_16x16x32_bf16(af[m], Q[c], acc[m][c + 4], 0, 0, 0);
        __builtin_amdgcn_s_setprio(0);
        af[0] = afn[0]; af[1] = afn[1];
      }
    } else {
      for (int step = 0; step < 8; ++step){
        bf16x8 af[2], bfr[8];
        #pragma unroll
        for (int m = 0; m < 2; ++m){
          int row = m * 16 + ln;
          int chunk = step * 4 + g;
          af[m] = *(const bf16x8*)&ub[row * 256 + ((chunk ^ (row & 7)) << 3)];
        }
        #pragma unroll
        for (int c = 0; c < 4; ++c){
          int col = w * 64 + c * 16 + ln;
          #pragma unroll
          for (int j = 0; j < 8; ++j){
            bfr[c][j]     = (short)f2bf(Wl[(step * 32 + g * 8 + j) * 256 + col]);
            bfr[c + 4][j] = (short)f2bf(Wr[(step * 32 + g * 8 + j) * 256 + col]);
          }
        }
        #pragma unroll
        for (int m = 0; m < 2; ++m)
          #pragma unroll
          for (int c = 0; c < 8; ++c)
            acc[m][c] = __builtin_amdgcn_mfma_f32_16x16x32_bf16(af[m], bfr[c], acc[m][c], 0, 0, 0);
      }
    }

    // ---- cross-tile prefetch setup
    const int ntile = tile + stride;
    const bool have = ntile < ntiles;
    const float* nb = hin + (size_t)ntile * 8192;
    unsigned short* un = &uni[(cur ^ 1) * 8192];
    float4 hA0, hA1, hB0, hB1, hC0, hC1, hD0, hD1;   // pair A = chunks t, t+256
    if (have){
      int q0 = t;            // chunk ids
      int q1 = t + 256;
      hA0 = *(const float4*)(nb + (q0 >> 5) * 256 + (q0 & 31) * 8);
      hA1 = *(const float4*)(nb + (q0 >> 5) * 256 + (q0 & 31) * 8 + 4);
      hB0 = *(const float4*)(nb + (q1 >> 5) * 256 + (q1 & 31) * 8);
      hB1 = *(const float4*)(nb + (q1 >> 5) * 256 + (q1 & 31) * 8 + 4);
    }

    // ---- attention m = 0 (R17 verbatim)
    {
      const int m = 0;
      float e[16];
      #pragma unroll
      for (int q = 0; q < 16; ++q) e[q] = 0.f;
      #pragma unroll
      for (int c = 0; c < 4; ++c){
        f32x4 GL = acc[m][c];
        f32x4 GR = acc[m][c + 4];
        #pragma unroll
        for (int i = 0; i < 4; ++i)
          #pragma unroll
          for (int j = 0; j < 4; ++j){
            float x = GL[i] + GR[j];
            x = fmaxf(x, SLOPE * x);
            e[i * 4 + j] = fmaf(x, av[c], e[i * 4 + j]);
          }
      }
      #pragma unroll
      for (int mask = 1; mask <= 8; mask <<= 1)
        #pragma unroll
        for (int q = 0; q < 16; ++q)
          e[q] += __shfl_xor(e[q], mask);
      #pragma unroll
      for (int q = 0; q < 16; ++q) e[q] += eb_s[q];
      #pragma unroll
      for (int i = 0; i < 4; ++i){
        float mx = fmaxf(fmaxf(e[i*4+0], e[i*4+1]), fmaxf(e[i*4+2], e[i*4+3]));
        float p0 = __expf(e[i*4+0] - mx);
        float p1 = __expf(e[i*4+1] - mx);
        float p2 = __expf(e[i*4+2] - mx);
        float p3 = __expf(e[i*4+3] - mx);
        float rs = 1.f / (p0 + p1 + p2 + p3);
        e[i*4+0] = p0 * rs; e[i*4+1] = p1 * rs; e[i*4+2] = p2 * rs; e[i*4+3] = p3 * rs;
      }
      float hp[4][4];
      #pragma unroll
      for (int i = 0; i < 4; ++i){
        #pragma unroll
        for (int c = 0; c < 4; ++c){
          f32x4 GR = acc[m][c + 4];
          float v = e[i*4+0] * GR[0];
          v = fmaf(e[i*4+1], GR[1], v);
          v = fmaf(e[i*4+2], GR[2], v);
          v = fmaf(e[i*4+3], GR[3], v);
          hp[i][c] = v;
        }
        float s1 = hp[i][0] + hp[i][1] + hp[i][2] + hp[i][3];
        float s2 = fmaf(hp[i][0], hp[i][0],
                   fmaf(hp[i][1], hp[i][1],
                   fmaf(hp[i][2], hp[i][2], hp[i][3] * hp[i][3])));
        #pragma unroll
        for (int mask = 1; mask <= 8; mask <<= 1){
          s1 += __shfl_xor(s1, mask);
          s2 += __shfl_xor(s2, mask);
        }
        int r = (m * 4 + g) * 4 + i;
        if (ln == 0){ red1[r * 4 + w] = s1; red2[r * 4 + w] = s2; }
      }
      __syncthreads();

      // prefetch: issue pair B loads, then write pair A to the other half
      if (have){
        int q2 = t + 512;
        int q3 = t + 768;
        hC0 = *(const float4*)(nb + (q2 >> 5) * 256 + (q2 & 31) * 8);
        hC1 = *(const float4*)(nb + (q2 >> 5) * 256 + (q2 & 31) * 8 + 4);
        hD0 = *(const float4*)(nb + (q3 >> 5) * 256 + (q3 & 31) * 8);
        hD1 = *(const float4*)(nb + (q3 >> 5) * 256 + (q3 & 31) * 8 + 4);
        {
          int q0 = t, row = q0 >> 5, c = q0 & 31;
          bf16x8 v;
          v[0]=(short)f2bf(hA0.x); v[1]=(short)f2bf(hA0.y); v[2]=(short)f2bf(hA0.z); v[3]=(short)f2bf(hA0.w);
          v[4]=(short)f2bf(hA1.x); v[5]=(short)f2bf(hA1.y); v[6]=(short)f2bf(hA1.z); v[7]=(short)f2bf(hA1.w);
          *(bf16x8*)&un[row * 256 + ((c ^ (row & 7)) << 3)] = v;
        }
        {
          int q1 = t + 256, row = q1 >> 5, c = q1 & 31;
          bf16x8 v;
          v[0]=(short)f2bf(hB0.x); v[1]=(short)f2bf(hB0.y); v[2]=(short)f2bf(hB0.z); v[3]=(short)f2bf(hB0.w);
          v[4]=(short)f2bf(hB1.x); v[5]=(short)f2bf(hB1.y); v[6]=(short)f2bf(hB1.z); v[7]=(short)f2bf(hB1.w);
          *(bf16x8*)&un[row * 256 + ((c ^ (row & 7)) << 3)] = v;
        }
      }

      float gmr[4], btr[4];
      #pragma unroll
      for (int c = 0; c < 4; ++c){
        gmr[c] = gmw[w * 64 + c * 16 + ln];
        btr[c] = btw[w * 64 + c * 16 + ln];
      }
      #pragma unroll
      for (int i = 0; i < 4; ++i){
        int r = (m * 4 + g) * 4 + i;
        float4 v1 = *(const float4*)&red1[r * 4];
        float4 v2 = *(const float4*)&red2[r * 4];
        float s1 = (v1.x + v1.y) + (v1.z + v1.w);
        float s2 = (v2.x + v2.y) + (v2.z + v2.w);
        float mu = s1 * (1.f / 256.f);
        float var = s2 * (1.f / 256.f) - mu * mu;
        float inv = rsqrtf(var + LN_EPS);
        float* op = out + ((size_t)tile * 32 + r) * 256 + w * 64 + ln;
        #pragma unroll
        for (int c = 0; c < 4; ++c)
          op[c * 16] = fmaf((hp[i][c] - mu) * inv, gmr[c], btr[c]);
      }
    }

    // ---- attention m = 1 (R17 verbatim)
    {
      const int m = 1;
      float e[16];
      #pragma unroll
      for (int q = 0; q < 16; ++q) e[q] = 0.f;
      #pragma unroll
      for (int c = 0; c < 4; ++c){
        f32x4 GL = acc[m][c];
        f32x4 GR = acc[m][c + 4];
        #pragma unroll
        for (int i = 0; i < 4; ++i)
          #pragma unroll
          for (int j = 0; j < 4; ++j){
            float x = GL[i] + GR[j];
            x = fmaxf(x, SLOPE * x);
            e[i * 4 + j] = fmaf(x, av[c], e[i * 4 + j]);
          }
      }
      #pragma unroll
      for (int mask = 1; mask <= 8; mask <<= 1)
        #pragma unroll
        for (int q = 0; q < 16; ++q)
          e[q] += __shfl_xor(e[q], mask);
      #pragma unroll
      for (int q = 0; q < 16; ++q) e[q] += eb_s[q];
      #pragma unroll
      for (int i = 0; i < 4; ++i){
        float mx = fmaxf(fmaxf(e[i*4+0], e[i*4+1]), fmaxf(e[i*4+2], e[i*4+3]));
        float p0 = __expf(e[i*4+0] - mx);
        float p1 = __expf(e[i*4+1] - mx);
        float p2 = __expf(e[i*4+2] - mx);
        float p3 = __expf(e[i*4+3] - mx);
        float rs = 1.f / (p0 + p1 + p2 + p3);
        e[i*4+0] = p0 * rs; e[i*4+1] = p1 * rs; e[i*4+2] = p2 * rs; e[i*4+3] = p3 * rs;
      }
      float hp[4][4];
      #pragma unroll
      for (int i = 0; i < 4; ++i){
        #pragma unroll
        for (int c = 0; c < 4; ++c){
          f32x4 GR = acc[m][c + 4];
          float v = e[i*4+0] * GR[0];
          v = fmaf(e[i*4+1], GR[1], v);
          v = fmaf(e[i*4+2], GR[2], v);
          v = fmaf(e[i*4+3], GR[3], v);
          hp[i][c] = v;
        }
        float s1 = hp[i][0] + hp[i][1] + hp[i][2] + hp[i][3];
        float s2 = fmaf(hp[i][0], hp[i][0],
                   fmaf(hp[i][1], hp[i][1],
                   fmaf(hp[i][2], hp[i][2], hp[i][3] * hp[i][3])));
        #pragma unroll
        for (int mask = 1; mask <= 8; mask <<= 1){
          s1 += __shfl_xor(s1, mask);
          s2 += __shfl_xor(s2, mask);
        }
        int r = (m * 4 + g) * 4 + i;
        if (ln == 0){ red1[r * 4 + w] = s1; red2[r * 4 + w] = s2; }
      }
      __syncthreads();

      // prefetch: write pair B to the other half
      if (have){
        {
          int q2 = t + 512, row = q2 >> 5, c = q2 & 31;
          bf16x8 v;
          v[0]=(short)f2bf(hC0.x); v[1]=(short)f2bf(hC0.y); v[2]=(short)f2bf(hC0.z); v[3]=(short)f2bf(hC0.w);
          v[4]=(short)f2bf(hC1.x); v[5]=(short)f2bf(hC1.y); v[6]=(short)f2bf(hC1.z); v[7]=(short)f2bf(hC1.w);
          *(bf16x8*)&un[row * 256 + ((c ^ (row & 7)) << 3)] = v;
        }
        {
          int q3 = t + 768, row = q3 >> 5, c = q3 & 31;
          bf16x8 v;
          v[0]=(short)f2bf(hD0.x); v[1]=(short)f2bf(hD0.y); v[2]=(short)f2bf(hD0.z); v[3]=(short)f2bf(hD0.w);
          v[4]=(short)f2bf(hD1.x); v[5]=(short)f2bf(hD1.y); v[6]=(short)f2bf(hD1.z); v[7]=(short)f2bf(hD1.w);
          *(bf16x8*)&un[row * 256 + ((c ^ (row & 7)) << 3)] = v;
        }
      }

      float gmr[4], btr[4];
      #pragma unroll
      for (int c = 0; c < 4; ++c){
        gmr[c] = gmw[w * 64 + c * 16 + ln];
        btr[c] = btw[w * 64 + c * 16 + ln];
      }
      #pragma unroll
      for (int i = 0; i < 4; ++i){
        int r = (m * 4 + g) * 4 + i;
        float4 v1 = *(const float4*)&red1[r * 4];
        float4 v2 = *(const float4*)&red2[r * 4];
        float s1 = (v1.x + v1.y) + (v1.z + v1.w);
        float s2 = (v2.x + v2.y) + (v2.z + v2.w);
        float mu = s1 * (1.f / 256.f);
        float var = s2 * (1.f / 256.f) - mu * mu;
        float inv = rsqrtf(var + LN_EPS);
        float* op = out + ((size_t)tile * 32 + r) * 256 + w * 64 + ln;
        #pragma unroll
        for (int c = 0; c < 4; ++c)
          op[c * 16] = fmaf((hp[i][c] - mu) * inv, gmr[c], btr[c]);
      }
    }

    if (!have) break;
    tile = ntile;
    cur ^= 1;
  }
}

extern "C" void kernel_launch(void* const* d_in, const int* in_sizes, int n_in,
                              void* d_out, int out_size, void* d_ws, size_t ws_size,
                              hipStream_t stream){
  const float* h  = (const float*)d_in[0];
  const float* eb = (const float*)d_in[1];
  const float* Wl = (const float*)d_in[2];
  const float* Wr = (const float*)d_in[3];
  const float* a  = (const float*)d_in[4];
  const float* gm = (const float*)d_in[5];
  const float* bt = (const float*)d_in[6];
  float* out = (float*)d_out;
  (void)n_in; (void)out_size;

  int B = in_sizes[0] / 1024;        // (B, 4, 256) f32
  int ntiles = B / 8;

  if (ws_size >= 262144){
    unsigned short* wbf = (unsigned short*)d_ws;
    wconv_kernel<<<64, 256, 0, stream>>>(Wl, Wr, wbf);
    int nblk = (ntiles < 768) ? ntiles : 768;   // persistent: ~3 blocks/CU
    gat_fused<true><<<nblk, 256, 0, stream>>>(h, eb, Wl, Wr, a, gm, bt, wbf, out, ntiles);
  } else {
    gat_fused<false><<<ntiles, 256, 0, stream>>>(h, eb, Wl, Wr, a, gm, bt, nullptr, out, ntiles);
  }
}

// Round 19
// 92.732 us; speedup vs baseline: 3.2128x; 3.2128x over previous
//
#include <hip/hip_runtime.h>
#include <hip/hip_bf16.h>

typedef short bf16x8 __attribute__((ext_vector_type(8)));
typedef float f32x4 __attribute__((ext_vector_type(4)));

#define LN_EPS 1e-5f
#define SLOPE 0.2f

// Native conversion: compiler fuses adjacent pairs to v_cvt_pk_bf16_f32 (m240).
__device__ __forceinline__ unsigned short f2bf(float f){
  __hip_bfloat16 b = __float2bfloat16(f);
  return *reinterpret_cast<unsigned short*>(&b);
}

// Verified W image (rounds 1..17):
// wbf[((s*4+g)*512 + c)*8 + j] = W[k = s*32+g*8+j][c]   (c<256: W_l, else W_r)
__global__ void wconv_kernel(const float* __restrict__ Wl,
                             const float* __restrict__ Wr,
                             unsigned short* __restrict__ wbf){
  int idx = blockIdx.x * 256 + threadIdx.x;   // 0..16383 : (s,g,c)
  int c = idx & 511;
  int gg = (idx >> 9) & 3;
  int s = idx >> 11;
  int k0 = s * 32 + gg * 8;
  const float* src = (c < 256) ? (Wl + c) : (Wr + (c - 256));
  bf16x8 v;
  #pragma unroll
  for (int j = 0; j < 8; ++j) v[j] = (short)f2bf(src[(k0 + j) * 256]);
  *(bf16x8*)&wbf[(size_t)idx * 8] = v;
}

// R17 verified base (95.6 us) with SINGLE-BARRIER attention:
// compute(m0) -> compute(m1) -> one barrier -> epilogue(m0) -> epilogue(m1).
// Red ranges are disjoint per m (r 0..15 vs 16..31), so one barrier suffices;
// m0's serial LN shuffle-DS chains now hide under m1's e-phase VALU block.
// LN reductions batched per m (8 independent chains per mask round).
// All value-computation order per element is unchanged -> bit-identical output.
// NOTE: minwaves/EU >= 4 in __launch_bounds__ MISCOMPILES (R5->R6 test). Keep 2.
// NOTE: persistent blocks / register prefetch across phases SPILLS (R10, R18).
template<bool USE_WS>
__global__ __launch_bounds__(256, 2)
void gat_fused(const float* __restrict__ hin, const float* __restrict__ ebias,
               const float* __restrict__ Wl, const float* __restrict__ Wr,
               const float* __restrict__ avec, const float* __restrict__ gmw,
               const float* __restrict__ btw, const unsigned short* __restrict__ wbf,
               float* __restrict__ out){
  __shared__ __align__(16) unsigned short uni[8192];    // h-tile [32][256] bf16, 16KB
  __shared__ float red1[128], red2[128];                // [row][wave] LN partials
  __shared__ float eb_s[16];

  const int t = threadIdx.x;
  const int lane = t & 63;
  const int w = t >> 6;
  const int b0 = blockIdx.x * 8;
  const int g = lane >> 4;
  const int ln = lane & 15;

  float av[4];
  #pragma unroll
  for (int c = 0; c < 4; ++c) av[c] = avec[w * 64 + c * 16 + ln];
  if (t < 16) eb_s[t] = ebias[t];

  // ---- stage h tile (32 rows x 256 k) f32->bf16, XOR-swizzled (verified R4)
  {
    const float* hb = hin + (size_t)b0 * 1024;
    #pragma unroll
    for (int it = 0; it < 4; ++it){
      int q = it * 256 + t;              // 16B-chunk id, 1024 total
      int row = q >> 5;
      int c = q & 31;
      const float* src = hb + row * 256 + c * 8;
      float4 f0 = *(const float4*)src;
      float4 f1 = *(const float4*)(src + 4);
      bf16x8 v;
      v[0]=(short)f2bf(f0.x); v[1]=(short)f2bf(f0.y); v[2]=(short)f2bf(f0.z); v[3]=(short)f2bf(f0.w);
      v[4]=(short)f2bf(f1.x); v[5]=(short)f2bf(f1.y); v[6]=(short)f2bf(f1.z); v[7]=(short)f2bf(f1.w);
      *(bf16x8*)&uni[row * 256 + ((c ^ (row & 7)) << 3)] = v;
    }
  }
  __syncthreads();

  f32x4 acc[2][8];
  #pragma unroll
  for (int m = 0; m < 2; ++m)
    #pragma unroll
    for (int c = 0; c < 8; ++c)
      acc[m][c] = (f32x4){0.f, 0.f, 0.f, 0.f};

  // ---- pipelined K loop (R17 verbatim)
  if constexpr (USE_WS){
    const unsigned short* wbase = wbf + (size_t)g * 4096 + (size_t)(w * 64 + ln) * 8;
    bf16x8 af[2], afn[2], P[4], Q[4];
    #pragma unroll
    for (int m = 0; m < 2; ++m)
      af[m] = *(const bf16x8*)&uni[(m * 16 + ln) * 256 + ((g ^ (ln & 7)) << 3)];
    #pragma unroll
    for (int c = 0; c < 4; ++c)
      P[c] = *(const bf16x8*)(wbase + c * 128);          // gl(0)

    #pragma unroll
    for (int step = 0; step < 8; ++step){
      const unsigned short* wp = wbase + (size_t)step * 16384;
      #pragma unroll
      for (int c = 0; c < 4; ++c)
        Q[c] = *(const bf16x8*)(wp + 2048 + c * 128);    // gr(step)
      if (step < 7){
        #pragma unroll
        for (int m = 0; m < 2; ++m)
          afn[m] = *(const bf16x8*)&uni[(m * 16 + ln) * 256
                     + ((((step + 1) * 4 + g) ^ (ln & 7)) << 3)];
      }
      __builtin_amdgcn_s_setprio(1);
      #pragma unroll
      for (int m = 0; m < 2; ++m)
        #pragma unroll
        for (int c = 0; c < 4; ++c)
          acc[m][c] = __builtin_amdgcn_mfma_f32_16x16x32_bf16(af[m], P[c], acc[m][c], 0, 0, 0);
      __builtin_amdgcn_s_setprio(0);
      if (step < 7){
        const unsigned short* wpn = wp + 16384;
        #pragma unroll
        for (int c = 0; c < 4; ++c)
          P[c] = *(const bf16x8*)(wpn + c * 128);        // gl(step+1)
      }
      __builtin_amdgcn_s_setprio(1);
      #pragma unroll
      for (int m = 0; m < 2; ++m)
        #pragma unroll
        for (int c = 0; c < 4; ++c)
          acc[m][c + 4] = __builtin_amdgcn_mfma_f32_16x16x32_bf16(af[m], Q[c], acc[m][c + 4], 0, 0, 0);
      __builtin_amdgcn_s_setprio(0);
      af[0] = afn[0]; af[1] = afn[1];
    }
  } else {
    for (int step = 0; step < 8; ++step){
      bf16x8 af[2], bfr[8];
      #pragma unroll
      for (int m = 0; m < 2; ++m){
        int row = m * 16 + ln;
        int chunk = step * 4 + g;
        af[m] = *(const bf16x8*)&uni[row * 256 + ((chunk ^ (row & 7)) << 3)];
      }
      #pragma unroll
      for (int c = 0; c < 4; ++c){
        int col = w * 64 + c * 16 + ln;
        #pragma unroll
        for (int j = 0; j < 8; ++j){
          bfr[c][j]     = (short)f2bf(Wl[(step * 32 + g * 8 + j) * 256 + col]);
          bfr[c + 4][j] = (short)f2bf(Wr[(step * 32 + g * 8 + j) * 256 + col]);
        }
      }
      #pragma unroll
      for (int m = 0; m < 2; ++m)
        #pragma unroll
        for (int c = 0; c < 8; ++c)
          acc[m][c] = __builtin_amdgcn_mfma_f32_16x16x32_bf16(af[m], bfr[c], acc[m][c], 0, 0, 0);
    }
  }

  // ---- attention compute for BOTH m (no barrier between; values R17-identical)
  float hp[2][4][4];
  #pragma unroll
  for (int m = 0; m < 2; ++m){
    float e[16];
    #pragma unroll
    for (int q = 0; q < 16; ++q) e[q] = 0.f;
    #pragma unroll
    for (int c = 0; c < 4; ++c){
      f32x4 GL = acc[m][c];
      f32x4 GR = acc[m][c + 4];
      #pragma unroll
      for (int i = 0; i < 4; ++i)
        #pragma unroll
        for (int j = 0; j < 4; ++j){
          float x = GL[i] + GR[j];
          x = fmaxf(x, SLOPE * x);        // leaky_relu
          e[i * 4 + j] = fmaf(x, av[c], e[i * 4 + j]);
        }
    }
    #pragma unroll
    for (int mask = 1; mask <= 8; mask <<= 1)
      #pragma unroll
      for (int q = 0; q < 16; ++q)
        e[q] += __shfl_xor(e[q], mask);
    #pragma unroll
    for (int q = 0; q < 16; ++q) e[q] += eb_s[q];
    #pragma unroll
    for (int i = 0; i < 4; ++i){
      float mx = fmaxf(fmaxf(e[i*4+0], e[i*4+1]), fmaxf(e[i*4+2], e[i*4+3]));
      float p0 = __expf(e[i*4+0] - mx);
      float p1 = __expf(e[i*4+1] - mx);
      float p2 = __expf(e[i*4+2] - mx);
      float p3 = __expf(e[i*4+3] - mx);
      float rs = 1.f / (p0 + p1 + p2 + p3);
      e[i*4+0] = p0 * rs; e[i*4+1] = p1 * rs; e[i*4+2] = p2 * rs; e[i*4+3] = p3 * rs;
    }
    // PV + LN partials, batched: hp/s first, then 8 independent shuffle chains
    float s1[4], s2[4];
    #pragma unroll
    for (int i = 0; i < 4; ++i){
      #pragma unroll
      for (int c = 0; c < 4; ++c){
        f32x4 GR = acc[m][c + 4];
        float v = e[i*4+0] * GR[0];
        v = fmaf(e[i*4+1], GR[1], v);
        v = fmaf(e[i*4+2], GR[2], v);
        v = fmaf(e[i*4+3], GR[3], v);
        hp[m][i][c] = v;
      }
      s1[i] = hp[m][i][0] + hp[m][i][1] + hp[m][i][2] + hp[m][i][3];
      s2[i] = fmaf(hp[m][i][0], hp[m][i][0],
              fmaf(hp[m][i][1], hp[m][i][1],
              fmaf(hp[m][i][2], hp[m][i][2], hp[m][i][3] * hp[m][i][3])));
    }
    #pragma unroll
    for (int mask = 1; mask <= 8; mask <<= 1)
      #pragma unroll
      for (int i = 0; i < 4; ++i){
        s1[i] += __shfl_xor(s1[i], mask);
        s2[i] += __shfl_xor(s2[i], mask);
      }
    #pragma unroll
    for (int i = 0; i < 4; ++i){
      int r = (m * 4 + g) * 4 + i;        // m=0: 0..15, m=1: 16..31 (disjoint)
      if (ln == 0){ red1[r * 4 + w] = s1[i]; red2[r * 4 + w] = s2[i]; }
    }
  }
  __syncthreads();                        // single barrier for both m

  // ---- epilogues (read red + own hp; gm/bt loaded once)
  float gmr[4], btr[4];
  #pragma unroll
  for (int c = 0; c < 4; ++c){
    gmr[c] = gmw[w * 64 + c * 16 + ln];
    btr[c] = btw[w * 64 + c * 16 + ln];
  }
  #pragma unroll
  for (int m = 0; m < 2; ++m)
    #pragma unroll
    for (int i = 0; i < 4; ++i){
      int r = (m * 4 + g) * 4 + i;
      float4 v1 = *(const float4*)&red1[r * 4];
      float4 v2 = *(const float4*)&red2[r * 4];
      float s1 = (v1.x + v1.y) + (v1.z + v1.w);
      float s2 = (v2.x + v2.y) + (v2.z + v2.w);
      float mu = s1 * (1.f / 256.f);
      float var = s2 * (1.f / 256.f) - mu * mu;
      float inv = rsqrtf(var + LN_EPS);
      float* op = out + ((size_t)b0 * 4 + r) * 256 + w * 64 + ln;
      #pragma unroll
      for (int c = 0; c < 4; ++c)
        op[c * 16] = fmaf((hp[m][i][c] - mu) * inv, gmr[c], btr[c]);
    }
}

extern "C" void kernel_launch(void* const* d_in, const int* in_sizes, int n_in,
                              void* d_out, int out_size, void* d_ws, size_t ws_size,
                              hipStream_t stream){
  const float* h  = (const float*)d_in[0];
  const float* eb = (const float*)d_in[1];
  const float* Wl = (const float*)d_in[2];
  const float* Wr = (const float*)d_in[3];
  const float* a  = (const float*)d_in[4];
  const float* gm = (const float*)d_in[5];
  const float* bt = (const float*)d_in[6];
  float* out = (float*)d_out;
  (void)n_in; (void)out_size;

  int B = in_sizes[0] / 1024;        // (B, 4, 256) f32
  int nblk = B / 8;

  if (ws_size >= 262144){
    unsigned short* wbf = (unsigned short*)d_ws;
    wconv_kernel<<<64, 256, 0, stream>>>(Wl, Wr, wbf);
    gat_fused<true><<<nblk, 256, 0, stream>>>(h, eb, Wl, Wr, a, gm, bt, wbf, out);
  } else {
    gat_fused<false><<<nblk, 256, 0, stream>>>(h, eb, Wl, Wr, a, gm, bt, nullptr, out);
  }
}